// Round 1
// baseline (108.465 us; speedup 1.0000x reference)
//
#include <hip/hip_runtime.h>
#include <hip/hip_bf16.h>

// SoftmaxLossRScore: mean(relu(logsumexp(A @ Neg^T, axis=1) - rowdot(A,P) + r + 1))
// B=2048, N=32768, D=128. Strategy: bf16 MFMA fused GEMM+sumexp (no [B,N]
// materialization, no online max needed -- scores bounded ~±60, exp fits fp32).
// A is pre-scaled by log2(e) so epilogue is exp2 (bare v_exp_f32).

#define B_ROWS 2048
#define N_NEG  32768
#define DIM    128
#define LOG2E  1.4426950408889634f
#define LN2    0.6931471805599453f

typedef __bf16 bf16x8 __attribute__((ext_vector_type(8)));
typedef float  f32x4  __attribute__((ext_vector_type(4)));

static __device__ inline unsigned short f2bf(float f) {
    union { float f; unsigned u; } v; v.f = f;
    unsigned r = v.u + 0x7FFF + ((v.u >> 16) & 1);   // round-to-nearest-even
    return (unsigned short)(r >> 16);
}

static __device__ inline void load_lds16(const void* g, void* s) {
    __builtin_amdgcn_global_load_lds(
        (const __attribute__((address_space(1))) void*)g,
        (__attribute__((address_space(3))) void*)s,
        16, 0, 0);
}

// ---------- P1: anchor -> bf16*log2e, pos_sim, zero sumexp ------------------
// 256 blocks x 256 thr; 8 rows/block, 32 lanes/row, 4 floats/lane.
__global__ void prep_anchor(const float* __restrict__ anchor,
                            const float* __restrict__ positive,
                            unsigned short* __restrict__ a_bf,
                            float* __restrict__ pos_sim,
                            float* __restrict__ sumexp) {
    int t   = threadIdx.x;
    int row = blockIdx.x * 8 + (t >> 5);
    int c4  = (t & 31) * 4;
    const float4 a4 = *(const float4*)(anchor   + row * DIM + c4);
    const float4 p4 = *(const float4*)(positive + row * DIM + c4);
    float dot = a4.x * p4.x + a4.y * p4.y + a4.z * p4.z + a4.w * p4.w;
    ushort4 ab;
    ab.x = f2bf(a4.x * LOG2E); ab.y = f2bf(a4.y * LOG2E);
    ab.z = f2bf(a4.z * LOG2E); ab.w = f2bf(a4.w * LOG2E);
    *(ushort4*)(a_bf + row * DIM + c4) = ab;
    #pragma unroll
    for (int m = 1; m <= 16; m <<= 1) dot += __shfl_xor(dot, m, 64);
    if ((t & 31) == 0) { pos_sim[row] = dot; sumexp[row] = 0.0f; }
}

// ---------- P2: negative -> bf16 (unscaled) ---------------------------------
// 1024 blocks x 256 thr; 4 float4 per thread, grid-strided.
__global__ void conv_neg(const float* __restrict__ neg,
                         unsigned short* __restrict__ n_bf) {
    int i = blockIdx.x * 256 + threadIdx.x;   // float4 index
    #pragma unroll
    for (int k = 0; k < 4; k++) {
        int idx = i + k * (1024 * 256);
        float4 v = *(const float4*)(neg + (size_t)idx * 4);
        ushort4 o;
        o.x = f2bf(v.x); o.y = f2bf(v.y); o.z = f2bf(v.z); o.w = f2bf(v.w);
        *(ushort4*)(n_bf + (size_t)idx * 4) = o;
    }
}

// ---------- main: fused bf16 GEMM + sum(exp2) -------------------------------
// Grid 512 = 16 row-tiles x 32 N-chunks. Block 256 thr = 4 waves (2x2).
// Block tile 128 rows x 1024 cols, inner BN=128. A-frags register-resident.
// LDS 64 KB: region0 = A then odd B tiles; region1 = even B tiles (dbuf).
#define CHUNK 1024
#define TSTEPS (CHUNK / 128)   // 8

__global__ __launch_bounds__(256, 2) void fused_gemm_lse(
        const unsigned short* __restrict__ A,
        const unsigned short* __restrict__ Nb,
        float* __restrict__ sumexp) {
    __shared__ unsigned short lds[2][128 * 128];   // 2 x 32 KB

    const int bid     = blockIdx.x;
    const int rowTile = bid & 15;
    const int chunk   = bid >> 4;
    const int wave = threadIdx.x >> 6, lane = threadIdx.x & 63;
    const int wr = wave >> 1, wc = wave & 1;
    const int q = lane >> 4, c = lane & 15;

    // stage A tile (contiguous 32 KB) -> region0, B(0) -> region1
    const unsigned short* Ag = A + rowTile * (128 * DIM);
    const unsigned short* Bg = Nb + (size_t)(chunk * CHUNK) * DIM;
    #pragma unroll
    for (int i = 0; i < 8; i++) {
        int off = wave * 4096 + i * 512;           // ushort units (1 KB per instr)
        load_lds16(Ag + off + lane * 8, &lds[0][off]);
        load_lds16(Bg + off + lane * 8, &lds[1][off]);
    }
    asm volatile("s_waitcnt vmcnt(0)" ::: "memory");
    __syncthreads();

    // preload A fragments: wave rows = wr*64 .. +64, 4 subtiles x 4 k-steps
    bf16x8 af[4][4];
    #pragma unroll
    for (int i = 0; i < 4; i++)
        #pragma unroll
        for (int k = 0; k < 4; k++)
            af[i][k] = *(const bf16x8*)&lds[0][(wr * 64 + i * 16 + c) * DIM + k * 32 + q * 8];
    __syncthreads();   // region0 now free for B(1)

    const f32x4 zero4 = {0.f, 0.f, 0.f, 0.f};
    f32x4 sumacc[4] = {zero4, zero4, zero4, zero4};

    for (int t = 0; t < TSTEPS; t++) {
        const int cur = 1 - (t & 1);
        const int nxt = t & 1;
        if (t + 1 < TSTEPS) {                      // async prefetch B(t+1)
            const unsigned short* Bn = Bg + (size_t)(t + 1) * 128 * DIM;
            #pragma unroll
            for (int i = 0; i < 8; i++) {
                int off = wave * 4096 + i * 512;
                load_lds16(Bn + off + lane * 8, &lds[nxt][off]);
            }
        }
        #pragma unroll
        for (int j = 0; j < 4; j++) {              // wave cols = wc*64 + j*16
            bf16x8 bf[4];
            #pragma unroll
            for (int k = 0; k < 4; k++)
                bf[k] = *(const bf16x8*)&lds[cur][(wc * 64 + j * 16 + c) * DIM + k * 32 + q * 8];
            #pragma unroll
            for (int i = 0; i < 4; i++) {
                f32x4 acc = __builtin_amdgcn_mfma_f32_16x16x32_bf16(af[i][0], bf[0], zero4, 0, 0, 0);
                acc = __builtin_amdgcn_mfma_f32_16x16x32_bf16(af[i][1], bf[1], acc, 0, 0, 0);
                acc = __builtin_amdgcn_mfma_f32_16x16x32_bf16(af[i][2], bf[2], acc, 0, 0, 0);
                acc = __builtin_amdgcn_mfma_f32_16x16x32_bf16(af[i][3], bf[3], acc, 0, 0, 0);
                sumacc[i][0] += exp2f(acc[0]);
                sumacc[i][1] += exp2f(acc[1]);
                sumacc[i][2] += exp2f(acc[2]);
                sumacc[i][3] += exp2f(acc[3]);
            }
        }
        asm volatile("s_waitcnt vmcnt(0)" ::: "memory");
        __syncthreads();
    }

    // per-row combine: reduce the 16 column-lanes, then atomic into global
    #pragma unroll
    for (int i = 0; i < 4; i++) {
        #pragma unroll
        for (int r = 0; r < 4; r++) {
            float v = sumacc[i][r];
            v += __shfl_xor(v, 1, 64);
            v += __shfl_xor(v, 2, 64);
            v += __shfl_xor(v, 4, 64);
            v += __shfl_xor(v, 8, 64);
            if ((lane & 15) == 0) {
                int row = rowTile * 128 + wr * 64 + i * 16 + q * 4 + r;
                atomicAdd(&sumexp[row], v);
            }
        }
    }
}

// ---------- final: lse, relu, mean -> scalar --------------------------------
__global__ void finalize(const float* __restrict__ sumexp,
                         const float* __restrict__ pos_sim,
                         const float* __restrict__ r_score,
                         float* __restrict__ out) {
    __shared__ float red[4];
    int t = threadIdx.x;
    float acc = 0.0f;
    #pragma unroll
    for (int i = 0; i < 8; i++) {
        int row = t + i * 256;
        float lse  = __log2f(sumexp[row]) * LN2;   // A was pre-scaled by log2e
        float loss = lse - pos_sim[row] + r_score[row] + 1.0f;
        acc += fmaxf(loss, 0.0f);
    }
    #pragma unroll
    for (int m = 1; m <= 32; m <<= 1) acc += __shfl_xor(acc, m, 64);
    if ((t & 63) == 0) red[t >> 6] = acc;
    __syncthreads();
    if (t == 0) out[0] = (red[0] + red[1] + red[2] + red[3]) * (1.0f / (float)B_ROWS);
}

extern "C" void kernel_launch(void* const* d_in, const int* in_sizes, int n_in,
                              void* d_out, int out_size, void* d_ws, size_t ws_size,
                              hipStream_t stream) {
    const float* anchor   = (const float*)d_in[0];
    const float* positive = (const float*)d_in[1];
    const float* negative = (const float*)d_in[2];
    const float* r_score  = (const float*)d_in[3];
    float* out = (float*)d_out;

    char* ws = (char*)d_ws;
    float* sumexp           = (float*)ws;                       // 2048 f32
    float* pos_sim          = (float*)(ws + 8192);              // 2048 f32
    unsigned short* a_bf    = (unsigned short*)(ws + 16384);    // 512 KB
    unsigned short* n_bf    = (unsigned short*)(ws + 16384 + 524288); // 8 MB

    prep_anchor<<<256, 256, 0, stream>>>(anchor, positive, a_bf, pos_sim, sumexp);
    conv_neg<<<1024, 256, 0, stream>>>(negative, n_bf);
    fused_gemm_lse<<<512, 256, 0, stream>>>(a_bf, n_bf, sumexp);
    finalize<<<1, 256, 0, stream>>>(sumexp, pos_sim, r_score, out);
}

// Round 2
// 95.438 us; speedup vs baseline: 1.1365x; 1.1365x over previous
//
#include <hip/hip_runtime.h>
#include <hip/hip_bf16.h>

// SoftmaxLossRScore: mean(relu(logsumexp(A @ Neg^T, axis=1) - rowdot(A,P) + r + 1))
// B=2048, N=32768, D=128. bf16 MFMA fused GEMM+sumexp, no [B,N] materialization.
// A pre-scaled by log2(e) so epilogue is a bare v_exp_f32 (exp2).
// R2: XOR-swizzled LDS chunks (chunk ^= row&7) to kill the 16-way bank
// conflicts of 256B-row-major fragment reads (R1 post-mortem: ~30us lost).

#define B_ROWS 2048
#define N_NEG  32768
#define DIM    128
#define LOG2E  1.4426950408889634f
#define LN2    0.6931471805599453f

typedef __bf16 bf16x8 __attribute__((ext_vector_type(8)));
typedef float  f32x4  __attribute__((ext_vector_type(4)));

static __device__ inline unsigned short f2bf(float f) {
    union { float f; unsigned u; } v; v.f = f;
    unsigned r = v.u + 0x7FFF + ((v.u >> 16) & 1);   // round-to-nearest-even
    return (unsigned short)(r >> 16);
}

static __device__ inline void load_lds16(const void* g, void* s) {
    __builtin_amdgcn_global_load_lds(
        (const __attribute__((address_space(1))) void*)g,
        (__attribute__((address_space(3))) void*)s,
        16, 0, 0);
}

// ---------- P1 (merged): anchor->bf16*log2e + pos_sim + zero sumexp, neg->bf16
// blocks 0..255: anchor path (8 rows/block, 32 lanes/row, 4 floats/lane)
// blocks 256..1279: negative conversion (grid-strided ushort4)
__global__ void prep(const float* __restrict__ anchor,
                     const float* __restrict__ positive,
                     const float* __restrict__ neg,
                     unsigned short* __restrict__ a_bf,
                     unsigned short* __restrict__ n_bf,
                     float* __restrict__ pos_sim,
                     float* __restrict__ sumexp) {
    int t = threadIdx.x;
    if (blockIdx.x < 256) {
        int row = blockIdx.x * 8 + (t >> 5);
        int c4  = (t & 31) * 4;
        const float4 a4 = *(const float4*)(anchor   + row * DIM + c4);
        const float4 p4 = *(const float4*)(positive + row * DIM + c4);
        float dot = a4.x * p4.x + a4.y * p4.y + a4.z * p4.z + a4.w * p4.w;
        ushort4 ab;
        ab.x = f2bf(a4.x * LOG2E); ab.y = f2bf(a4.y * LOG2E);
        ab.z = f2bf(a4.z * LOG2E); ab.w = f2bf(a4.w * LOG2E);
        *(ushort4*)(a_bf + row * DIM + c4) = ab;
        #pragma unroll
        for (int m = 1; m <= 16; m <<= 1) dot += __shfl_xor(dot, m, 64);
        if ((t & 31) == 0) { pos_sim[row] = dot; sumexp[row] = 0.0f; }
    } else {
        int i = (blockIdx.x - 256) * 256 + t;   // float4 index
        #pragma unroll
        for (int k = 0; k < 4; k++) {
            int idx = i + k * (1024 * 256);
            float4 v = *(const float4*)(neg + (size_t)idx * 4);
            ushort4 o;
            o.x = f2bf(v.x); o.y = f2bf(v.y); o.z = f2bf(v.z); o.w = f2bf(v.w);
            *(ushort4*)(n_bf + (size_t)idx * 4) = o;
        }
    }
}

// ---------- main: fused bf16 GEMM + sum(exp2) -------------------------------
// Grid 512 = 16 row-tiles x 32 N-chunks. Block 256 thr = 4 waves (2x2).
// Block tile 128 rows x 1024 cols, inner BN=128. A-frags register-resident.
// LDS 64 KB: region0 = A then odd B tiles; region1 = even B tiles (dbuf).
// LDS rows are 256 B; 16B chunk j of row r stored at slot j, holding global
// chunk j^(r&7)  (swizzle applied on the global source address -- the
// global_load_lds lane->LDS mapping is fixed).
#define CHUNK 1024
#define TSTEPS (CHUNK / 128)   // 8

__global__ __launch_bounds__(256, 2) void fused_gemm_lse(
        const unsigned short* __restrict__ A,
        const unsigned short* __restrict__ Nb,
        float* __restrict__ sumexp) {
    __shared__ unsigned short lds[2][128 * 128];   // 2 x 32 KB

    const int bid     = blockIdx.x;
    const int rowTile = bid & 15;
    const int chunk   = bid >> 4;
    const int wave = threadIdx.x >> 6, lane = threadIdx.x & 63;
    const int wr = wave >> 1, wc = wave & 1;
    const int q = lane >> 4, c = lane & 15;
    const int lrow = lane >> 4;       // staging: row within 4-row group
    const int lchk = lane & 15;       // staging: 16B chunk within row

    const unsigned short* Ag = A + rowTile * (128 * DIM);
    const unsigned short* Bg = Nb + (size_t)(chunk * CHUNK) * DIM;

    // stage A tile -> region0, B(0) -> region1 (swizzled global source)
    #pragma unroll
    for (int i = 0; i < 8; i++) {
        int off = wave * 4096 + i * 512;            // ushort offset, 4 rows
        int r   = (off >> 7) + lrow;                // absolute row in tile
        int gofs = r * DIM + ((lchk ^ (r & 7)) << 3);
        load_lds16(Ag + gofs, &lds[0][off]);
        load_lds16(Bg + gofs, &lds[1][off]);
    }
    asm volatile("s_waitcnt vmcnt(0)" ::: "memory");
    __syncthreads();

    // swizzled k-step chunk offsets (ushort units), invariant across t/j:
    // chunk(k) for this lane = (k*4+q) ^ (c&7)
    int swz[4];
    #pragma unroll
    for (int k = 0; k < 4; k++) swz[k] = (((k * 4 + q) ^ (c & 7)) << 3);

    // preload A fragments: wave rows wr*64..+64, 4 subtiles x 4 k-steps
    bf16x8 af[4][4];
    #pragma unroll
    for (int i = 0; i < 4; i++) {
        int row = wr * 64 + i * 16 + c;
        #pragma unroll
        for (int k = 0; k < 4; k++)
            af[i][k] = *(const bf16x8*)&lds[0][row * DIM + swz[k]];
    }
    __syncthreads();   // region0 now free for B(1)

    const f32x4 zero4 = {0.f, 0.f, 0.f, 0.f};
    f32x4 sumacc[4] = {zero4, zero4, zero4, zero4};

    for (int t = 0; t < TSTEPS; t++) {
        const int cur = 1 - (t & 1);
        const int nxt = t & 1;
        if (t + 1 < TSTEPS) {                      // async prefetch B(t+1)
            const unsigned short* Bn = Bg + (size_t)(t + 1) * 128 * DIM;
            #pragma unroll
            for (int i = 0; i < 8; i++) {
                int off = wave * 4096 + i * 512;
                int r   = (off >> 7) + lrow;
                int gofs = r * DIM + ((lchk ^ (r & 7)) << 3);
                load_lds16(Bn + gofs, &lds[nxt][off]);
            }
        }
        #pragma unroll
        for (int j = 0; j < 4; j++) {              // wave cols = wc*64 + j*16
            int brow = wc * 64 + j * 16 + c;
            bf16x8 bf[4];
            #pragma unroll
            for (int k = 0; k < 4; k++)
                bf[k] = *(const bf16x8*)&lds[cur][brow * DIM + swz[k]];
            #pragma unroll
            for (int i = 0; i < 4; i++) {
                f32x4 acc = __builtin_amdgcn_mfma_f32_16x16x32_bf16(af[i][0], bf[0], zero4, 0, 0, 0);
                acc = __builtin_amdgcn_mfma_f32_16x16x32_bf16(af[i][1], bf[1], acc, 0, 0, 0);
                acc = __builtin_amdgcn_mfma_f32_16x16x32_bf16(af[i][2], bf[2], acc, 0, 0, 0);
                acc = __builtin_amdgcn_mfma_f32_16x16x32_bf16(af[i][3], bf[3], acc, 0, 0, 0);
                sumacc[i][0] += __builtin_amdgcn_exp2f(acc[0]);
                sumacc[i][1] += __builtin_amdgcn_exp2f(acc[1]);
                sumacc[i][2] += __builtin_amdgcn_exp2f(acc[2]);
                sumacc[i][3] += __builtin_amdgcn_exp2f(acc[3]);
            }
        }
        if (t + 1 < TSTEPS) {
            asm volatile("s_waitcnt vmcnt(0)" ::: "memory");
            __syncthreads();
        }
    }

    // per-row combine: reduce 16 column-lanes, atomic into global
    #pragma unroll
    for (int i = 0; i < 4; i++) {
        #pragma unroll
        for (int r = 0; r < 4; r++) {
            float v = sumacc[i][r];
            v += __shfl_xor(v, 1, 64);
            v += __shfl_xor(v, 2, 64);
            v += __shfl_xor(v, 4, 64);
            v += __shfl_xor(v, 8, 64);
            if ((lane & 15) == 0) {
                int row = rowTile * 128 + wr * 64 + i * 16 + q * 4 + r;
                atomicAdd(&sumexp[row], v);
            }
        }
    }
}

// ---------- final: lse, relu, mean -> scalar --------------------------------
__global__ void finalize(const float* __restrict__ sumexp,
                         const float* __restrict__ pos_sim,
                         const float* __restrict__ r_score,
                         float* __restrict__ out) {
    __shared__ float red[4];
    int t = threadIdx.x;
    float acc = 0.0f;
    #pragma unroll
    for (int i = 0; i < 8; i++) {
        int row = t + i * 256;
        float lse  = __log2f(sumexp[row]) * LN2;   // A was pre-scaled by log2e
        float loss = lse - pos_sim[row] + r_score[row] + 1.0f;
        acc += fmaxf(loss, 0.0f);
    }
    #pragma unroll
    for (int m = 1; m <= 32; m <<= 1) acc += __shfl_xor(acc, m, 64);
    if ((t & 63) == 0) red[t >> 6] = acc;
    __syncthreads();
    if (t == 0) out[0] = (red[0] + red[1] + red[2] + red[3]) * (1.0f / (float)B_ROWS);
}

extern "C" void kernel_launch(void* const* d_in, const int* in_sizes, int n_in,
                              void* d_out, int out_size, void* d_ws, size_t ws_size,
                              hipStream_t stream) {
    const float* anchor   = (const float*)d_in[0];
    const float* positive = (const float*)d_in[1];
    const float* negative = (const float*)d_in[2];
    const float* r_score  = (const float*)d_in[3];
    float* out = (float*)d_out;

    char* ws = (char*)d_ws;
    float* sumexp           = (float*)ws;                       // 2048 f32
    float* pos_sim          = (float*)(ws + 8192);              // 2048 f32
    unsigned short* a_bf    = (unsigned short*)(ws + 16384);    // 512 KB
    unsigned short* n_bf    = (unsigned short*)(ws + 16384 + 524288); // 8 MB

    prep<<<1280, 256, 0, stream>>>(anchor, positive, negative, a_bf, n_bf, pos_sim, sumexp);
    fused_gemm_lse<<<512, 256, 0, stream>>>(a_bf, n_bf, sumexp);
    finalize<<<1, 256, 0, stream>>>(sumexp, pos_sim, r_score, out);
}